// Round 1
// baseline (4024.236 us; speedup 1.0000x reference)
//
#include <hip/hip_runtime.h>

typedef short short8_t __attribute__((ext_vector_type(8)));
typedef float f32x4 __attribute__((ext_vector_type(4)));

__device__ __forceinline__ unsigned short f2bf(float x) {
    unsigned int u = __float_as_uint(x);
    unsigned int r = (u + 0x7fffu + ((u >> 16) & 1u)) >> 16;
    return (unsigned short)r;
}
__device__ __forceinline__ float bf2f(unsigned short s) {
    return __uint_as_float(((unsigned int)s) << 16);
}

// ---------------- GEMM: C[M,N] = A[M,K](fp32) @ B[N,K]^T(fp32) + bias[N] ----------------
// MODE 1: C written as bf16, plain [M,N].
// MODE 2: FC epilogue: fp32, row=(t*32+b) -> out[b][t+1][col]; rows>=2016 dropped.
template<int MODE>
__global__ __launch_bounds__(256) void gemm_bt(
    const float* __restrict__ A, const float* __restrict__ B,
    const float* __restrict__ bias, void* __restrict__ Cv,
    int M, int N, int K)
{
    __shared__ __align__(16) unsigned short As[128 * 64];
    __shared__ __align__(16) unsigned short Bs[128 * 64];
    const int tid = threadIdx.x;
    const int bn = blockIdx.x, bm = blockIdx.y;
    const int m0 = bm * 128, n0 = bn * 128;
    const int lane = tid & 63, wid = tid >> 6;
    const int wr = wid >> 1, wc = wid & 1;
    const int la = lane & 15, lb = lane >> 4;
    f32x4 acc[4][4] = {};
    for (int k0 = 0; k0 < K; k0 += 64) {
        #pragma unroll
        for (int i = 0; i < 8; ++i) {
            int c = tid + 256 * i;
            int r = c >> 4, c4 = c & 15;
            int byo = (r * 128 + c4 * 8) ^ ((r & 7) << 4);   // XOR-swizzle vs 16-way bank conflict
            float4 va = *reinterpret_cast<const float4*>(A + (size_t)(m0 + r) * K + k0 + c4 * 4);
            ushort4 pa = make_ushort4(f2bf(va.x), f2bf(va.y), f2bf(va.z), f2bf(va.w));
            *reinterpret_cast<ushort4*>(reinterpret_cast<char*>(As) + byo) = pa;
            float4 vb = *reinterpret_cast<const float4*>(B + (size_t)(n0 + r) * K + k0 + c4 * 4);
            ushort4 pb = make_ushort4(f2bf(vb.x), f2bf(vb.y), f2bf(vb.z), f2bf(vb.w));
            *reinterpret_cast<ushort4*>(reinterpret_cast<char*>(Bs) + byo) = pb;
        }
        __syncthreads();
        #pragma unroll
        for (int kk = 0; kk < 2; ++kk) {
            short8_t af[4], bfr[4];
            #pragma unroll
            for (int m = 0; m < 4; ++m) {
                int r = wr * 64 + m * 16 + la;
                int byo = (r * 128 + kk * 64 + lb * 16) ^ ((r & 7) << 4);
                af[m] = *reinterpret_cast<const short8_t*>(reinterpret_cast<const char*>(As) + byo);
            }
            #pragma unroll
            for (int n = 0; n < 4; ++n) {
                int r = wc * 64 + n * 16 + la;
                int byo = (r * 128 + kk * 64 + lb * 16) ^ ((r & 7) << 4);
                bfr[n] = *reinterpret_cast<const short8_t*>(reinterpret_cast<const char*>(Bs) + byo);
            }
            #pragma unroll
            for (int m = 0; m < 4; ++m)
                #pragma unroll
                for (int n = 0; n < 4; ++n)
                    acc[m][n] = __builtin_amdgcn_mfma_f32_16x16x32_bf16(af[m], bfr[n], acc[m][n], 0, 0, 0);
        }
        __syncthreads();
    }
    #pragma unroll
    for (int m = 0; m < 4; ++m) {
        #pragma unroll
        for (int n = 0; n < 4; ++n) {
            int col = n0 + wc * 64 + n * 16 + la;
            float bv = bias ? bias[col] : 0.f;
            #pragma unroll
            for (int g = 0; g < 4; ++g) {
                int row = m0 + wr * 64 + m * 16 + lb * 4 + g;
                float v = acc[m][n][g] + bv;
                if (MODE == 1) {
                    reinterpret_cast<unsigned short*>(Cv)[(size_t)row * N + col] = f2bf(v);
                } else {
                    if (row < 2016) {
                        int t = row >> 5, b = row & 31;
                        reinterpret_cast<float*>(Cv)[((size_t)b * 64 + t + 1) * 32000 + col] = v;
                    }
                }
            }
        }
    }
}

// ---------------- LSTM step: gates = G[t] + h_in @ Whh^T ; update c, h_out ----------------
struct StepArgs {
    const float* h_in;            // [32][H] fp32
    float* c;                     // [32][H] fp32, in-place
    const unsigned short* G;      // [32][4H] bf16 (input-part + bias, this timestep)
    const float* Whh;             // [4H][H] fp32
    float* h_out;                 // [32][H] fp32
};

__global__ __launch_bounds__(512) void lstm_step(StepArgs a0, StepArgs a1, int hlog)
{
    __shared__ __align__(16) unsigned short h_lds[16 * 1028];
    __shared__ float red[4][512];
    const StepArgs a = (blockIdx.y == 0) ? a0 : a1;
    const int H = 1 << hlog;
    const int PS = H + 4;                 // bank-spread pad (short2 stride)
    const int tid = threadIdx.x;
    const int ublk = blockIdx.x >> 1, bg = blockIdx.x & 1;
    const int f4_per_row = H >> 2;
    for (int i = tid; i < 16 * f4_per_row; i += 512) {
        int r = i >> (hlog - 2);
        int c4 = i & (f4_per_row - 1);
        float4 v = *reinterpret_cast<const float4*>(a.h_in + (size_t)(bg * 16 + r) * H + c4 * 4);
        ushort4 p = make_ushort4(f2bf(v.x), f2bf(v.y), f2bf(v.z), f2bf(v.w));
        *reinterpret_cast<ushort4*>(&h_lds[r * PS + c4 * 4]) = p;
    }
    __syncthreads();
    const int kh = tid >> 7;              // k-range quarter
    const int u_loc = (tid >> 4) & 7;
    const int bl = tid & 15;
    const int u = ublk * 8 + u_loc;
    const float4* wi = reinterpret_cast<const float4*>(a.Whh + (size_t)u * H);
    const float4* wf = reinterpret_cast<const float4*>(a.Whh + (size_t)(H + u) * H);
    const float4* wg = reinterpret_cast<const float4*>(a.Whh + (size_t)(2 * H + u) * H);
    const float4* wo = reinterpret_cast<const float4*>(a.Whh + (size_t)(3 * H + u) * H);
    float ai = 0.f, af = 0.f, ag = 0.f, ao = 0.f;
    const int k4beg = kh * (H >> 4), k4end = (kh + 1) * (H >> 4);
    const char* hrow = reinterpret_cast<const char*>(&h_lds[bl * PS]);
    for (int k4 = k4beg; k4 < k4end; ++k4) {
        uint2 hp = *reinterpret_cast<const uint2*>(hrow + k4 * 8);
        float h0 = __uint_as_float(hp.x << 16);
        float h1 = __uint_as_float(hp.x & 0xffff0000u);
        float h2 = __uint_as_float(hp.y << 16);
        float h3 = __uint_as_float(hp.y & 0xffff0000u);
        float4 v;
        v = wi[k4]; ai += v.x * h0 + v.y * h1 + v.z * h2 + v.w * h3;
        v = wf[k4]; af += v.x * h0 + v.y * h1 + v.z * h2 + v.w * h3;
        v = wg[k4]; ag += v.x * h0 + v.y * h1 + v.z * h2 + v.w * h3;
        v = wo[k4]; ao += v.x * h0 + v.y * h1 + v.z * h2 + v.w * h3;
    }
    red[0][tid] = ai; red[1][tid] = af; red[2][tid] = ag; red[3][tid] = ao;
    __syncthreads();
    if (tid < 128) {
        float gi = red[0][tid] + red[0][tid + 128] + red[0][tid + 256] + red[0][tid + 384];
        float gf = red[1][tid] + red[1][tid + 128] + red[1][tid + 256] + red[1][tid + 384];
        float gg = red[2][tid] + red[2][tid + 128] + red[2][tid + 256] + red[2][tid + 384];
        float go = red[3][tid] + red[3][tid + 128] + red[3][tid + 256] + red[3][tid + 384];
        const int b = bg * 16 + (tid & 15);
        const int uu = ublk * 8 + ((tid >> 4) & 7);
        const size_t gbase = (size_t)b * (H << 2);
        gi += bf2f(a.G[gbase + uu]);
        gf += bf2f(a.G[gbase + H + uu]);
        gg += bf2f(a.G[gbase + 2 * H + uu]);
        go += bf2f(a.G[gbase + 3 * H + uu]);
        float co = a.c[(size_t)b * H + uu];
        float si = 1.f / (1.f + expf(-gi));
        float sf = 1.f / (1.f + expf(-gf));
        float so = 1.f / (1.f + expf(-go));
        float cn = sf * co + si * tanhf(gg);
        float hn = so * tanhf(cn);
        a.c[(size_t)b * H + uu] = cn;
        a.h_out[(size_t)b * H + uu] = hn;
    }
}

// ---------------- small utility kernels ----------------
__global__ void k_embed_enc(const int* __restrict__ src, const float* __restrict__ emb,
                            float* __restrict__ xe)
{
    int m = blockIdx.x;                   // 0..4095, m = s*32 + b
    int s = m >> 5, b = m & 31;
    int tok = src[b * 128 + s];
    reinterpret_cast<float4*>(xe)[(size_t)m * 64 + threadIdx.x] =
        reinterpret_cast<const float4*>(emb)[(size_t)tok * 64 + threadIdx.x];
}

__global__ void k_embed_dec(const int* __restrict__ trg, const float* __restrict__ emb,
                            float* __restrict__ dxe)
{
    int m = blockIdx.x;                   // 0..2047, m = t*32 + b
    int t = m >> 5, b = m & 31;
    float4 v = make_float4(0.f, 0.f, 0.f, 0.f);
    if (t < 63) {
        int tok = trg[b * 64 + t];
        v = reinterpret_cast<const float4*>(emb)[(size_t)tok * 64 + threadIdx.x];
    }
    reinterpret_cast<float4*>(dxe)[(size_t)m * 64 + threadIdx.x] = v;
}

__global__ void k_concat(const float* __restrict__ hf, const float* __restrict__ hb,
                         const float* __restrict__ cf, const float* __restrict__ cb,
                         float* __restrict__ hd, float* __restrict__ cd)
{
    int i = blockIdx.x * 256 + threadIdx.x;   // 0..32767
    int b = i >> 10, u = i & 1023;
    float hv = (u < 512) ? hf[b * 512 + u] : hb[b * 512 + u - 512];
    float cv = (u < 512) ? cf[b * 512 + u] : cb[b * 512 + u - 512];
    hd[i] = hv; cd[i] = cv;
}

__global__ void k_zero(float* __restrict__ p, int n)
{
    int i = blockIdx.x * 256 + threadIdx.x;
    if (i < n) p[i] = 0.f;
}

__global__ void k_zero_out(float* __restrict__ out)
{
    int i = blockIdx.x * 256 + threadIdx.x;   // 0..1023999
    int b = i / 32000, v = i - b * 32000;
    out[(size_t)b * 2048000 + v] = 0.f;
}

// ---------------- launcher ----------------
extern "C" void kernel_launch(void* const* d_in, const int* in_sizes, int n_in,
                              void* d_out, int out_size, void* d_ws, size_t ws_size,
                              hipStream_t stream)
{
    const int*   src     = (const int*)d_in[0];
    const int*   trg     = (const int*)d_in[1];
    const float* enc_emb = (const float*)d_in[2];
    const float* dec_emb = (const float*)d_in[3];
    const float* eWih_f  = (const float*)d_in[4];
    const float* eWhh_f  = (const float*)d_in[5];
    const float* eb_f    = (const float*)d_in[6];
    const float* eWih_b  = (const float*)d_in[7];
    const float* eWhh_b  = (const float*)d_in[8];
    const float* eb_b    = (const float*)d_in[9];
    const float* dWih    = (const float*)d_in[10];
    const float* dWhh    = (const float*)d_in[11];
    const float* db      = (const float*)d_in[12];
    const float* fcW     = (const float*)d_in[13];
    const float* fcb     = (const float*)d_in[14];
    float* out = (float*)d_out;
    float* wsf = (float*)d_ws;

    // workspace layout (float offsets)
    float* cf  = wsf + 0;
    float* cb  = wsf + 16384;
    float* hf0 = wsf + 32768;
    float* hb0 = wsf + 49152;
    float* hf1 = wsf + 65536;
    float* hb1 = wsf + 81920;
    float* hd0 = wsf + 98304;       // [32][1024]
    float* cd  = wsf + 131072;      // [32][1024]
    float* xe  = wsf + 163840;      // [4096][256]
    float* dxe = wsf + 1212416;     // [2048][256]
    float* hs  = wsf + 1736704;     // [2048][1024]
    unsigned short* Gf = (unsigned short*)(wsf + 3833856);   // [4096][2048] bf16
    unsigned short* Gb = Gf + (size_t)8388608;               // [4096][2048] bf16
    unsigned short* Gd = Gb + (size_t)8388608;               // [2048][4096] bf16
    float* hfp[2] = { hf0, hf1 };
    float* hbp[2] = { hb0, hb1 };

    // init: zero cf,cb,hf0,hb0 (contiguous 65536 floats), hs pad rows, out[:,0,:]
    k_zero<<<256, 256, 0, stream>>>(wsf, 65536);
    k_zero<<<128, 256, 0, stream>>>(hs + (size_t)2016 * 1024, 32768);
    k_zero_out<<<4000, 256, 0, stream>>>(out);

    // embeddings
    k_embed_enc<<<4096, 64, 0, stream>>>(src, enc_emb, xe);
    k_embed_dec<<<2048, 64, 0, stream>>>(trg, dec_emb, dxe);

    // gate input-parts (time-parallel GEMMs), bf16 outputs with bias folded in
    gemm_bt<1><<<dim3(16, 32), 256, 0, stream>>>(xe,  eWih_f, eb_f, Gf, 4096, 2048, 256);
    gemm_bt<1><<<dim3(16, 32), 256, 0, stream>>>(xe,  eWih_b, eb_b, Gb, 4096, 2048, 256);
    gemm_bt<1><<<dim3(32, 16), 256, 0, stream>>>(dxe, dWih,   db,   Gd, 2048, 4096, 256);

    // encoder recurrence: 128 steps, both directions per launch (gridDim.y = 2)
    for (int t = 0; t < 128; ++t) {
        StepArgs af_ = { hfp[t & 1], cf, Gf + (size_t)t * 65536,         eWhh_f, hfp[(t + 1) & 1] };
        StepArgs ab_ = { hbp[t & 1], cb, Gb + (size_t)(127 - t) * 65536, eWhh_b, hbp[(t + 1) & 1] };
        lstm_step<<<dim3(128, 2), 512, 0, stream>>>(af_, ab_, 9);
    }

    // h0/c0 = concat of final fwd/bwd states (finals land in hf0/hb0 after 128 steps)
    k_concat<<<128, 256, 0, stream>>>(hf0, hb0, cf, cb, hd0, cd);

    // decoder recurrence: 63 steps; h history stored in hs (FC's A matrix)
    for (int t = 0; t < 63; ++t) {
        StepArgs ad = { t ? hs + (size_t)(t - 1) * 32768 : hd0,
                        cd, Gd + (size_t)t * 131072, dWhh, hs + (size_t)t * 32768 };
        lstm_step<<<dim3(256, 1), 512, 0, stream>>>(ad, ad, 10);
    }

    // FC: logits -> out[b][t+1][v]
    gemm_bt<2><<<dim3(250, 16), 256, 0, stream>>>(hs, fcW, fcb, out, 2048, 32000, 1024);
}

// Round 2
// 2413.374 us; speedup vs baseline: 1.6675x; 1.6675x over previous
//
#include <hip/hip_runtime.h>

typedef short short8_t __attribute__((ext_vector_type(8)));
typedef unsigned short ushort8_t __attribute__((ext_vector_type(8)));
typedef float f32x4 __attribute__((ext_vector_type(4)));

static __device__ __forceinline__ unsigned short f2bf(float x) {
    unsigned int u = __float_as_uint(x);
    unsigned int r = (u + 0x7fffu + ((u >> 16) & 1u)) >> 16;
    return (unsigned short)r;
}
static __device__ __forceinline__ float bf2f(unsigned short s) {
    return __uint_as_float(((unsigned int)s) << 16);
}

// ---------------- GEMM: C[M,N] = A[M,K] @ B[N,K]^T(fp32) + bias[N] ----------------
// MODE 1: A fp32, C written as bf16 [M][N]; grid (bn, bm).
// MODE 2: A bf16, FC epilogue: fp32, row=(t*32+b) -> out[b][t+1][col]; rows>=2016
//         dropped; grid (bm, bn) so 16 row-blocks sharing a B panel run together.
template<int MODE>
__global__ __launch_bounds__(256) void gemm_bt(
    const void* __restrict__ Av, const float* __restrict__ B,
    const float* __restrict__ bias, void* __restrict__ Cv,
    int M, int N, int K)
{
    __shared__ __align__(16) unsigned short As[128 * 64];
    __shared__ __align__(16) unsigned short Bs[128 * 64];
    const int tid = threadIdx.x;
    const int bn = (MODE == 2) ? blockIdx.y : blockIdx.x;
    const int bm = (MODE == 2) ? blockIdx.x : blockIdx.y;
    const int m0 = bm * 128, n0 = bn * 128;
    const int lane = tid & 63, wid = tid >> 6;
    const int wr = wid >> 1, wc = wid & 1;
    const int la = lane & 15, lb = lane >> 4;
    f32x4 acc[4][4] = {};
    for (int k0 = 0; k0 < K; k0 += 64) {
        if (MODE == 2) {
            const unsigned short* Ab = (const unsigned short*)Av;
            #pragma unroll
            for (int i = 0; i < 4; ++i) {
                int c = tid + 256 * i;          // 0..1023 chunks of 8 bf16
                int r = c >> 3, c8 = c & 7;
                int byo = (r * 128 + c8 * 16) ^ ((r & 7) << 4);
                *reinterpret_cast<ushort8_t*>(reinterpret_cast<char*>(As) + byo) =
                    *reinterpret_cast<const ushort8_t*>(Ab + (size_t)(m0 + r) * K + k0 + c8 * 8);
            }
        } else {
            const float* A = (const float*)Av;
            #pragma unroll
            for (int i = 0; i < 8; ++i) {
                int c = tid + 256 * i;
                int r = c >> 4, c4 = c & 15;
                int byo = (r * 128 + c4 * 8) ^ ((r & 7) << 4);
                float4 va = *reinterpret_cast<const float4*>(A + (size_t)(m0 + r) * K + k0 + c4 * 4);
                ushort4 pa = make_ushort4(f2bf(va.x), f2bf(va.y), f2bf(va.z), f2bf(va.w));
                *reinterpret_cast<ushort4*>(reinterpret_cast<char*>(As) + byo) = pa;
            }
        }
        #pragma unroll
        for (int i = 0; i < 8; ++i) {
            int c = tid + 256 * i;
            int r = c >> 4, c4 = c & 15;
            int byo = (r * 128 + c4 * 8) ^ ((r & 7) << 4);
            float4 vb = *reinterpret_cast<const float4*>(B + (size_t)(n0 + r) * K + k0 + c4 * 4);
            ushort4 pb = make_ushort4(f2bf(vb.x), f2bf(vb.y), f2bf(vb.z), f2bf(vb.w));
            *reinterpret_cast<ushort4*>(reinterpret_cast<char*>(Bs) + byo) = pb;
        }
        __syncthreads();
        #pragma unroll
        for (int kk = 0; kk < 2; ++kk) {
            short8_t af[4], bfr[4];
            #pragma unroll
            for (int m = 0; m < 4; ++m) {
                int r = wr * 64 + m * 16 + la;
                int byo = (r * 128 + kk * 64 + lb * 16) ^ ((r & 7) << 4);
                af[m] = *reinterpret_cast<const short8_t*>(reinterpret_cast<const char*>(As) + byo);
            }
            #pragma unroll
            for (int n = 0; n < 4; ++n) {
                int r = wc * 64 + n * 16 + la;
                int byo = (r * 128 + kk * 64 + lb * 16) ^ ((r & 7) << 4);
                bfr[n] = *reinterpret_cast<const short8_t*>(reinterpret_cast<const char*>(Bs) + byo);
            }
            #pragma unroll
            for (int m = 0; m < 4; ++m)
                #pragma unroll
                for (int n = 0; n < 4; ++n)
                    acc[m][n] = __builtin_amdgcn_mfma_f32_16x16x32_bf16(af[m], bfr[n], acc[m][n], 0, 0, 0);
        }
        __syncthreads();
    }
    #pragma unroll
    for (int m = 0; m < 4; ++m) {
        #pragma unroll
        for (int n = 0; n < 4; ++n) {
            int col = n0 + wc * 64 + n * 16 + la;
            float bv = bias ? bias[col] : 0.f;
            #pragma unroll
            for (int g = 0; g < 4; ++g) {
                int row = m0 + wr * 64 + m * 16 + lb * 4 + g;
                float v = acc[m][n][g] + bv;
                if (MODE == 1) {
                    reinterpret_cast<unsigned short*>(Cv)[(size_t)row * N + col] = f2bf(v);
                } else {
                    if (row < 2016) {
                        int t = row >> 5, b = row & 31;
                        reinterpret_cast<float*>(Cv)[((size_t)b * 64 + t + 1) * 32000 + col] = v;
                    }
                }
            }
        }
    }
}

// ---------------- MFMA LSTM step ----------------
// gates[4K,32] = Whh_bf[4K,K] @ h_in^T ; += G ; pointwise -> c, h_out.
// Wave = 16 gate-rows = 4 units x 4 gates (row-permuted A fragments).
// 128 blocks x 128 threads (2 waves). NSETS=2: blocks 0..63 set a0, 64..127 set a1.
struct StepArgs {
    const unsigned short* h_in;   // [32][K] bf16
    float* c;                     // [32][K] fp32, in-place
    const unsigned short* G;      // [32][4K] bf16 (x@Wih^T + b, this timestep)
    const unsigned short* Whh;    // [4K][K] bf16
    unsigned short* h_out;        // [32][K] bf16
};

template<int K, int NSETS>
__global__ __launch_bounds__(128) void lstm_step(StepArgs a0, StepArgs a1)
{
    __shared__ float cbuf[2][16][33];
    const int tid = threadIdx.x;
    const int lane = tid & 63, w = tid >> 6;
    StepArgs a = a0;
    int gwave;
    if (NSETS == 2) {
        if (blockIdx.x >= 64) a = a1;
        gwave = (blockIdx.x & 63) * 2 + w;     // 0..127 -> units 0..508
    } else {
        gwave = blockIdx.x * 2 + w;            // 0..255 -> units 0..1020
    }
    const int U = gwave * 4;
    const int la = lane & 15, lb = lane >> 4;
    const int q = la >> 2, v = la & 3;         // A-tile row la -> gate q, unit U+v
    const unsigned short* arow = a.Whh + (size_t)(q * K + U + v) * K + lb * 8;
    const unsigned short* b0row = a.h_in + (size_t)la * K + lb * 8;
    const unsigned short* b1row = a.h_in + (size_t)(16 + la) * K + lb * 8;
    f32x4 acc0 = {}, acc1 = {};
    #pragma unroll 8
    for (int kk = 0; kk < K / 32; ++kk) {
        short8_t av  = *reinterpret_cast<const short8_t*>(arow + kk * 32);
        short8_t bv0 = *reinterpret_cast<const short8_t*>(b0row + kk * 32);
        short8_t bv1 = *reinterpret_cast<const short8_t*>(b1row + kk * 32);
        acc0 = __builtin_amdgcn_mfma_f32_16x16x32_bf16(av, bv0, acc0, 0, 0, 0);
        acc1 = __builtin_amdgcn_mfma_f32_16x16x32_bf16(av, bv1, acc1, 0, 0, 0);
    }
    #pragma unroll
    for (int g = 0; g < 4; ++g) {              // C[r=lb*4+g][col] ; col = batch
        cbuf[w][lb * 4 + g][la]      = acc0[g];
        cbuf[w][lb * 4 + g][16 + la] = acc1[g];
    }
    __syncthreads();
    #pragma unroll
    for (int p = 0; p < 2; ++p) {
        int flat = p * 64 + lane;              // 0..127 = 4 units x 32 batches
        int vv = flat >> 5, b = flat & 31;
        int uu = U + vv;
        float gi = cbuf[w][0 + vv][b];
        float gf = cbuf[w][4 + vv][b];
        float gg = cbuf[w][8 + vv][b];
        float go = cbuf[w][12 + vv][b];
        const unsigned short* Gb_ = a.G + (size_t)b * 4 * K;
        gi += bf2f(Gb_[uu]);
        gf += bf2f(Gb_[K + uu]);
        gg += bf2f(Gb_[2 * K + uu]);
        go += bf2f(Gb_[3 * K + uu]);
        float co = a.c[(size_t)b * K + uu];
        float si = 1.f / (1.f + expf(-gi));
        float sf = 1.f / (1.f + expf(-gf));
        float so = 1.f / (1.f + expf(-go));
        float cn = sf * co + si * tanhf(gg);
        float hn = so * tanhf(cn);
        a.c[(size_t)b * K + uu] = cn;
        a.h_out[(size_t)b * K + uu] = f2bf(hn);
    }
}

// ---------------- small utility kernels ----------------
__global__ void k_embed_enc(const int* __restrict__ src, const float* __restrict__ emb,
                            float* __restrict__ xe)
{
    int m = blockIdx.x;                   // m = s*32 + b
    int s = m >> 5, b = m & 31;
    int tok = src[b * 128 + s];
    reinterpret_cast<float4*>(xe)[(size_t)m * 64 + threadIdx.x] =
        reinterpret_cast<const float4*>(emb)[(size_t)tok * 64 + threadIdx.x];
}

__global__ void k_embed_dec(const int* __restrict__ trg, const float* __restrict__ emb,
                            float* __restrict__ dxe)
{
    int m = blockIdx.x;                   // m = t*32 + b
    int t = m >> 5, b = m & 31;
    float4 v = make_float4(0.f, 0.f, 0.f, 0.f);
    if (t < 63) {
        int tok = trg[b * 64 + t];
        v = reinterpret_cast<const float4*>(emb)[(size_t)tok * 64 + threadIdx.x];
    }
    reinterpret_cast<float4*>(dxe)[(size_t)m * 64 + threadIdx.x] = v;
}

__global__ void k_concat(const unsigned short* __restrict__ hf, const unsigned short* __restrict__ hb,
                         const float* __restrict__ cf, const float* __restrict__ cb,
                         unsigned short* __restrict__ hd, float* __restrict__ cd)
{
    int i = blockIdx.x * 256 + threadIdx.x;   // 0..32767
    int b = i >> 10, u = i & 1023;
    unsigned short hv = (u < 512) ? hf[b * 512 + u] : hb[b * 512 + u - 512];
    float cv = (u < 512) ? cf[b * 512 + u] : cb[b * 512 + u - 512];
    hd[i] = hv; cd[i] = cv;
}

__global__ void k_f2bf(const float* __restrict__ s, unsigned short* __restrict__ d, int n4)
{
    int i = blockIdx.x * 256 + threadIdx.x;
    if (i < n4) {
        float4 v = reinterpret_cast<const float4*>(s)[i];
        ushort4 p = make_ushort4(f2bf(v.x), f2bf(v.y), f2bf(v.z), f2bf(v.w));
        reinterpret_cast<ushort4*>(d)[i] = p;
    }
}

__global__ void k_zero(float* __restrict__ p, int n)
{
    int i = blockIdx.x * 256 + threadIdx.x;
    if (i < n) p[i] = 0.f;
}

__global__ void k_zero_out(float* __restrict__ out)
{
    int i = blockIdx.x * 256 + threadIdx.x;   // 0..1023999: out[b][0][v] = 0
    int b = i / 32000, v = i - b * 32000;
    out[(size_t)b * 2048000 + v] = 0.f;
}

// ---------------- launcher ----------------
extern "C" void kernel_launch(void* const* d_in, const int* in_sizes, int n_in,
                              void* d_out, int out_size, void* d_ws, size_t ws_size,
                              hipStream_t stream)
{
    const int*   src     = (const int*)d_in[0];
    const int*   trg     = (const int*)d_in[1];
    const float* enc_emb = (const float*)d_in[2];
    const float* dec_emb = (const float*)d_in[3];
    const float* eWih_f  = (const float*)d_in[4];
    const float* eWhh_f  = (const float*)d_in[5];
    const float* eb_f    = (const float*)d_in[6];
    const float* eWih_b  = (const float*)d_in[7];
    const float* eWhh_b  = (const float*)d_in[8];
    const float* eb_b    = (const float*)d_in[9];
    const float* dWih    = (const float*)d_in[10];
    const float* dWhh    = (const float*)d_in[11];
    const float* db      = (const float*)d_in[12];
    const float* fcW     = (const float*)d_in[13];
    const float* fcb     = (const float*)d_in[14];
    float* out = (float*)d_out;
    float* wsf = (float*)d_ws;

    // workspace layout (float offsets)
    float* cf  = wsf + 0;                                    // [32][512]
    float* cb  = wsf + 16384;                                // [32][512]
    float* cd  = wsf + 32768;                                // [32][1024]
    unsigned short* hf0 = (unsigned short*)(wsf + 65536);    // [32][512] bf16
    unsigned short* hf1 = (unsigned short*)(wsf + 73728);
    unsigned short* hb0 = (unsigned short*)(wsf + 81920);
    unsigned short* hb1 = (unsigned short*)(wsf + 90112);
    unsigned short* hd0 = (unsigned short*)(wsf + 98304);    // [32][1024] bf16
    unsigned short* hsb = (unsigned short*)(wsf + 114688);   // [2048][1024] bf16
    float* xe  = wsf + 1163264;                              // [4096][256] fp32
    float* dxe = wsf + 2211840;                              // [2048][256] fp32
    unsigned short* ewf_bf = (unsigned short*)(wsf + 2736128);  // [2048][512]
    unsigned short* ewb_bf = (unsigned short*)(wsf + 3260416);  // [2048][512]
    unsigned short* dwh_bf = (unsigned short*)(wsf + 3784704);  // [4096][1024]
    unsigned short* Gf = (unsigned short*)(wsf + 5881856);   // [4096][2048]
    unsigned short* Gb = (unsigned short*)(wsf + 10076160);  // [4096][2048]
    unsigned short* Gd = (unsigned short*)(wsf + 14270464);  // [2048][4096]
    unsigned short* hfp[2] = { hf0, hf1 };
    unsigned short* hbp[2] = { hb0, hb1 };

    // init: c states + h states zero; hsb pad rows zero; out[:,0,:] zero
    k_zero<<<256, 256, 0, stream>>>(wsf, 65536);             // cf, cb, cd
    k_zero<<<128, 256, 0, stream>>>(wsf + 65536, 32768);     // hf0,hf1,hb0,hb1
    k_zero<<<64, 256, 0, stream>>>(wsf + 1146880, 16384);    // hsb rows 2016..2047
    k_zero_out<<<4000, 256, 0, stream>>>(out);

    // weight conversions (bf16)
    k_f2bf<<<1024, 256, 0, stream>>>(eWhh_f, ewf_bf, 262144);
    k_f2bf<<<1024, 256, 0, stream>>>(eWhh_b, ewb_bf, 262144);
    k_f2bf<<<4096, 256, 0, stream>>>(dWhh, dwh_bf, 1048576);

    // embeddings
    k_embed_enc<<<4096, 64, 0, stream>>>(src, enc_emb, xe);
    k_embed_dec<<<2048, 64, 0, stream>>>(trg, dec_emb, dxe);

    // gate input-parts (time-parallel GEMMs), bf16 outputs with bias folded in
    gemm_bt<1><<<dim3(16, 32), 256, 0, stream>>>(xe,  eWih_f, eb_f, Gf, 4096, 2048, 256);
    gemm_bt<1><<<dim3(16, 32), 256, 0, stream>>>(xe,  eWih_b, eb_b, Gb, 4096, 2048, 256);
    gemm_bt<1><<<dim3(32, 16), 256, 0, stream>>>(dxe, dWih,   db,   Gd, 2048, 4096, 256);

    // encoder recurrence: 128 steps, both directions per launch
    for (int t = 0; t < 128; ++t) {
        StepArgs af_ = { hfp[t & 1], cf, Gf + (size_t)t * 65536,         ewf_bf, hfp[(t + 1) & 1] };
        StepArgs ab_ = { hbp[t & 1], cb, Gb + (size_t)(127 - t) * 65536, ewb_bf, hbp[(t + 1) & 1] };
        lstm_step<512, 2><<<128, 128, 0, stream>>>(af_, ab_);
    }

    // h0/c0 = concat of final fwd/bwd states (finals in hf0/hb0)
    k_concat<<<128, 256, 0, stream>>>(hf0, hb0, cf, cb, hd0, cd);

    // decoder recurrence: 63 steps; h history (bf16) is the FC's A matrix
    for (int t = 0; t < 63; ++t) {
        StepArgs ad = { t ? hsb + (size_t)(t - 1) * 32768 : hd0,
                        cd, Gd + (size_t)t * 131072, dwh_bf, hsb + (size_t)t * 32768 };
        lstm_step<1024, 1><<<128, 128, 0, stream>>>(ad, ad);
    }

    // FC: logits -> out[b][t+1][v]
    gemm_bt<2><<<dim3(16, 250), 256, 0, stream>>>(hsb, fcW, fcb, out, 2048, 32000, 1024);
}